// Round 1
// baseline (3417.141 us; speedup 1.0000x reference)
//
#include <hip/hip_runtime.h>

#pragma clang fp contract(off)

#define NBOX 4096
#define MBOX 256
#define NBATCH 32
#define GEPS 1e-7f
#define THREADS 1024
#define NWAVES (THREADS / 64)

// LDS layout for one batch's matching state (~48 KB)
struct SMem {
  unsigned long long rowmax[NBOX];                 // packed (val<<21)|((4096-r)<<8)|(255-col); 0 = removed
  float gx1[MBOX], gy1[MBOX], gx2[MBOX], gy2[MBOX], garea[MBOX];
  unsigned char colact[MBOX];
  unsigned short wl[NBOX];                         // rows needing rowmax recompute this step
  unsigned short mi[MBOX], mj[MBOX];               // match results
  unsigned long long warpmax[NWAVES];
  unsigned long long sel;
  int wl_count;
  float redA[NWAVES], redB[NWAVES];
};

__device__ __forceinline__ unsigned long long shflxor_u64(unsigned long long x, int m) {
  unsigned int lo = (unsigned int)x;
  unsigned int hi = (unsigned int)(x >> 32);
  lo = __shfl_xor(lo, m, 64);
  hi = __shfl_xor(hi, m, 64);
  return ((unsigned long long)hi << 32) | (unsigned long long)lo;
}

// torchvision generalized_box_iou_loss, elementwise (matches reference op order)
__device__ __forceinline__ float giou_loss(float ax1, float ay1, float ax2, float ay2,
                                           float bx1, float by1, float bx2, float by2) {
  #pragma clang fp contract(off)
  float xi1 = fmaxf(ax1, bx1), yi1 = fmaxf(ay1, by1);
  float xi2 = fminf(ax2, bx2), yi2 = fminf(ay2, by2);
  float inter = fmaxf(xi2 - xi1, 0.0f) * fmaxf(yi2 - yi1, 0.0f);
  float area1 = (ax2 - ax1) * (ay2 - ay1);
  float area2 = (bx2 - bx1) * (by2 - by1);
  float uni = (area1 + area2) - inter;
  float iou = inter / (uni + GEPS);
  float xc1 = fminf(ax1, bx1), yc1 = fminf(ay1, by1);
  float xc2 = fmaxf(ax2, bx2), yc2 = fmaxf(ay2, by2);
  float areac = (xc2 - xc1) * (yc2 - yc1);
  float giou = iou - (areac - uni) / (areac + GEPS);
  return 1.0f - giou;
}

// One wave recomputes row r's max IoU over active columns (first-col tiebreak),
// writes packed result into sm.rowmax[r].
__device__ __forceinline__ void wave_rowmax(int r, const float4* __restrict__ prb,
                                            SMem& sm, int lane) {
  #pragma clang fp contract(off)
  float4 a = prb[r];
  float areaA = (a.z - a.x) * (a.w - a.y);
  unsigned long long best = 0ull;  // (valbits<<8)|(255-c)
  #pragma unroll
  for (int k = 0; k < MBOX / 64; ++k) {
    int c = lane + 64 * k;
    if (sm.colact[c]) {
      float w = fminf(a.z, sm.gx2[c]) - fmaxf(a.x, sm.gx1[c]);
      float h = fminf(a.w, sm.gy2[c]) - fmaxf(a.y, sm.gy1[c]);
      w = fmaxf(w, 0.0f);
      h = fmaxf(h, 0.0f);
      float inter = w * h;                       // +0 when no overlap (never -0)
      float uni = (areaA + sm.garea[c]) - inter; // matches (area_a + area_b) - inter
      float v = inter / uni;                     // IoU >= 0, so bits are order-preserving
      unsigned long long p =
          ((unsigned long long)__float_as_uint(v) << 8) | (unsigned long long)(255 - c);
      if (p > best) best = p;
    }
  }
  #pragma unroll
  for (int o = 32; o; o >>= 1) {
    unsigned long long q = shflxor_u64(best, o);
    if (q > best) best = q;
  }
  if (lane == 0) {
    unsigned long long valbits = best >> 8;
    sm.rowmax[r] = (valbits << 21) | ((unsigned long long)(NBOX - r) << 8) | (best & 0xFFull);
  }
}

__global__ __launch_bounds__(THREADS) void match_loss_kernel(
    const float4* __restrict__ pr, const float4* __restrict__ gt,
    float* __restrict__ partial) {
  __shared__ SMem sm;
  const int b = blockIdx.x;
  const int tid = threadIdx.x;
  const int lane = tid & 63;
  const int wid = tid >> 6;
  const float4* prb = pr + (size_t)b * NBOX;
  const float4* gtb = gt + (size_t)b * MBOX;

  // stage gt boxes (SoA) + areas + column-active flags
  for (int c = tid; c < MBOX; c += THREADS) {
    float4 g = gtb[c];
    sm.gx1[c] = g.x; sm.gy1[c] = g.y; sm.gx2[c] = g.z; sm.gy2[c] = g.w;
    sm.garea[c] = (g.z - g.x) * (g.w - g.y);
    sm.colact[c] = 1;
  }
  __syncthreads();

  // initial per-row max: one wave per row
  for (int r = wid; r < NBOX; r += NWAVES) wave_rowmax(r, prb, sm, lane);
  __syncthreads();

  // greedy matching: 256 sequential selections
  for (int s = 0; s < MBOX; ++s) {
    // --- global argmax over rowmax[] (value desc, row asc, col asc) ---
    unsigned long long m = sm.rowmax[tid];
    #pragma unroll
    for (int k = 1; k < NBOX / THREADS; ++k) {
      unsigned long long q = sm.rowmax[tid + k * THREADS];
      if (q > m) m = q;
    }
    #pragma unroll
    for (int o = 32; o; o >>= 1) {
      unsigned long long q = shflxor_u64(m, o);
      if (q > m) m = q;
    }
    if (lane == 0) sm.warpmax[wid] = m;
    __syncthreads();  // B1
    if (wid == 0) {
      unsigned long long w = (lane < NWAVES) ? sm.warpmax[lane] : 0ull;
      #pragma unroll
      for (int o = 32; o; o >>= 1) {
        unsigned long long q = shflxor_u64(w, o);
        if (q > w) w = q;
      }
      if (lane == 0) { sm.sel = w; sm.wl_count = 0; }
    }
    __syncthreads();  // B2
    const unsigned long long selv = sm.sel;
    const int i = NBOX - (int)((selv >> 8) & 0x1FFFull);
    const int j = 255 - (int)(selv & 0xFFull);
    if (tid == 0) {
      sm.mi[s] = (unsigned short)i;
      sm.mj[s] = (unsigned short)j;
      sm.rowmax[i] = 0ull;   // remove row
      sm.colact[j] = 0;      // remove col
    }
    if (s == MBOX - 1) break;

    // --- rows whose current argmax column was just removed need recompute ---
    #pragma unroll
    for (int k = 0; k < NBOX / THREADS; ++k) {
      int r = tid + k * THREADS;
      if (r == i) continue;
      unsigned long long p = sm.rowmax[r];
      if (p != 0ull && (int)(p & 0xFFull) == 255 - j) {
        int idx = atomicAdd(&sm.wl_count, 1);
        sm.wl[idx] = (unsigned short)r;
      }
    }
    __syncthreads();  // B3 (wl final, colact[j]=0 and rowmax[i]=0 visible)
    const int cnt = sm.wl_count;
    for (int w = wid; w < cnt; w += NWAVES) wave_rowmax((int)sm.wl[w], prb, sm, lane);
    __syncthreads();  // B4
  }
  __syncthreads();  // make mi/mj of last step visible

  // --- losses ---
  // mean over matched pairs + mean over unmatched (= (sum_all - sum_matched)/3840)
  float possum = 0.0f, negdiff = 0.0f;
  for (int s = tid; s < MBOX; s += THREADS) {
    int ii = sm.mi[s], jj = sm.mj[s];
    float4 a = prb[ii];
    possum += giou_loss(a.x, a.y, a.z, a.w, sm.gx1[jj], sm.gy1[jj], sm.gx2[jj], sm.gy2[jj]);
    negdiff -= giou_loss(a.x, a.y, a.z, a.w, 0.0f, 0.0f, 0.0f, 0.0f);
  }
  for (int r = tid; r < NBOX; r += THREADS) {
    float4 a = prb[r];
    negdiff += giou_loss(a.x, a.y, a.z, a.w, 0.0f, 0.0f, 0.0f, 0.0f);
  }
  #pragma unroll
  for (int o = 32; o; o >>= 1) {
    possum  += __shfl_xor(possum, o, 64);
    negdiff += __shfl_xor(negdiff, o, 64);
  }
  if (lane == 0) { sm.redA[wid] = possum; sm.redB[wid] = negdiff; }
  __syncthreads();
  if (tid == 0) {
    float pa = 0.0f, nd = 0.0f;
    for (int w = 0; w < NWAVES; ++w) { pa += sm.redA[w]; nd += sm.redB[w]; }
    partial[b] = pa / 256.0f + nd / 3840.0f;
  }
}

__global__ void finalize_kernel(const float* __restrict__ partial, float* __restrict__ out) {
  if (threadIdx.x == 0) {
    float s = 0.0f;
    for (int i = 0; i < NBATCH; ++i) s += partial[i];
    out[0] = s / 64.0f;  // /count(=32)/2
  }
}

extern "C" void kernel_launch(void* const* d_in, const int* in_sizes, int n_in,
                              void* d_out, int out_size, void* d_ws, size_t ws_size,
                              hipStream_t stream) {
  (void)in_sizes; (void)n_in; (void)out_size; (void)ws_size;
  const float4* pr = (const float4*)d_in[0];
  const float4* gt = (const float4*)d_in[1];
  float* partial = (float*)d_ws;
  float* out = (float*)d_out;
  hipLaunchKernelGGL(match_loss_kernel, dim3(NBATCH), dim3(THREADS), 0, stream, pr, gt, partial);
  hipLaunchKernelGGL(finalize_kernel, dim3(1), dim3(64), 0, stream, partial, out);
}